// Round 7
// baseline (177.623 us; speedup 1.0000x reference)
//
#include <hip/hip_runtime.h>
#include <stdint.h>

#define C_DIM   256
#define L_ANCH  8
#define M_INST  64
#define NPIX    32768
#define TILE_M  32
#define LDSTR   264      // Fbuf row stride (shorts): 528 B
#define SSTR    260      // stash row stride (shorts)
#define WSTR    40       // prep W-tile row stride (shorts)

typedef __attribute__((ext_vector_type(8))) short  short8;   // 8 x bf16
typedef __attribute__((ext_vector_type(4))) float  float4v;  // MFMA C/D

__device__ __forceinline__ float bf2f(unsigned short b) {
    union { unsigned u; float f; } x; x.u = ((unsigned)b) << 16; return x.f;
}
__device__ __forceinline__ unsigned short f2bf(float f) {
    union { unsigned u; float f; } x; x.f = f;
    unsigned u = x.u;
    return (unsigned short)((u + 0x7FFFu + ((u >> 16) & 1u)) >> 16);  // RNE
}
__device__ __forceinline__ ushort4 f4bf(float4 f) {
    ushort4 v; v.x = f2bf(f.x); v.y = f2bf(f.y); v.z = f2bf(f.z); v.w = f2bf(f.w);
    return v;
}

// ---------------------------------------------------------------------------
// prep (unchanged): K/V projection + weight bf16 conversion
// ---------------------------------------------------------------------------
__global__ __launch_bounds__(256) void prep_kernel(
    const float* __restrict__ anchors, const float* __restrict__ in_proj_w,
    const float* __restrict__ in_proj_b, const float* __restrict__ out_w,
    unsigned short* __restrict__ Kb, unsigned short* __restrict__ Vb,
    unsigned short* __restrict__ Wqb, unsigned short* __restrict__ Owb)
{
    __shared__ unsigned short Abuf[32 * LDSTR];
    __shared__ unsigned short Wtile[4][64 * WSTR];
    const int b = blockIdx.x, t = threadIdx.x;

    if (b >= 32) {
        const int id = (b - 32) * 256 + t;
        if (id < 16384) {
            float4 f = *((const float4*)in_proj_w + id);
            *((ushort4*)Wqb + id) = f4bf(f);
        } else {
            float4 f = *((const float4*)out_w + (id - 16384));
            *((ushort4*)Owb + (id - 16384)) = f4bf(f);
        }
        return;
    }

    const int mat = b >> 4, tile = b & 15, m0 = tile * 32;
#pragma unroll
    for (int i = 0; i < 8; ++i) {
        int id = t + i * 256;
        int row = id >> 6, c4 = id & 63;
        float4 f = *((const float4*)(anchors + (size_t)(m0 + row) * C_DIM) + c4);
        *(ushort4*)&Abuf[row * LDSTR + c4 * 4] = f4bf(f);
    }
    __syncthreads();

    const int wave = t >> 6, lane = t & 63, r16 = lane & 15, quad = lane >> 4;
    const int wbase = C_DIM + mat * C_DIM + wave * 64;
    unsigned short* Wl = &Wtile[wave][0];

    float4v acc[2][4];
#pragma unroll
    for (int mt = 0; mt < 2; ++mt)
#pragma unroll
        for (int nt = 0; nt < 4; ++nt)
#pragma unroll
            for (int r = 0; r < 4; ++r) acc[mt][nt][r] = 0.f;

    for (int ks = 0; ks < 8; ++ks) {
        const int rr = lane >> 3, cc = lane & 7;
#pragma unroll
        for (int i = 0; i < 8; ++i) {
            int row = rr + i * 8;
            float4 f = *((const float4*)(in_proj_w + (size_t)(wbase + row) * C_DIM + ks * 32) + cc);
            *(ushort4*)&Wl[row * WSTR + cc * 4] = f4bf(f);
        }
        const int c0 = ks * 32 + quad * 8;
        short8 afr[2], bfr[4];
#pragma unroll
        for (int mt = 0; mt < 2; ++mt)
            afr[mt] = *(const short8*)&Abuf[(mt * 16 + r16) * LDSTR + c0];
#pragma unroll
        for (int nt = 0; nt < 4; ++nt)
            bfr[nt] = *(const short8*)&Wl[(nt * 16 + r16) * WSTR + quad * 8];
#pragma unroll
        for (int mt = 0; mt < 2; ++mt)
#pragma unroll
            for (int nt = 0; nt < 4; ++nt)
                acc[mt][nt] = __builtin_amdgcn_mfma_f32_16x16x32_bf16(
                    afr[mt], bfr[nt], acc[mt][nt], 0, 0, 0);
    }

    unsigned short* dst = mat ? Vb : Kb;
#pragma unroll
    for (int nt = 0; nt < 4; ++nt) {
        const int col = wave * 64 + nt * 16 + r16;
        const float bias = in_proj_b[C_DIM + mat * C_DIM + col];
#pragma unroll
        for (int mt = 0; mt < 2; ++mt)
#pragma unroll
            for (int r = 0; r < 4; ++r) {
                int row = m0 + mt * 16 + quad * 4 + r;
                dst[(size_t)row * C_DIM + col] = f2bf(acc[mt][nt][r] + bias);
            }
    }
}

// ---------------------------------------------------------------------------
// fused (R2 structure): 32 pixels/block, 1024 blocks, 4 blocks/CU.
//   Changes vs R2: (1) fully unrolled ks loops in both GEMMs,
//   (2) epilogue feature reloads prefetched into registers during attention.
// ---------------------------------------------------------------------------
__global__ __launch_bounds__(256, 4) void fused_kernel(
    const float* __restrict__ features, const int* __restrict__ inst,
    const float* __restrict__ in_proj_b, const float* __restrict__ out_b,
    const unsigned short* __restrict__ Wqb, const unsigned short* __restrict__ Owb,
    const unsigned short* __restrict__ Kb, const unsigned short* __restrict__ Vb,
    float* __restrict__ out)
{
    __shared__ unsigned short Fbuf[TILE_M * LDSTR];   // F -> Q -> O (16.9 KB)
    __shared__ unsigned short Stash[TILE_M * SSTR];   // masked GEMM2 result (16.6 KB)
    __shared__ int ilab[TILE_M];

    const int t = threadIdx.x;
    const int n0 = blockIdx.x * TILE_M;

    if (t < TILE_M) ilab[t] = inst[n0 + t];

    // ---- stage F tile bf16 (8 float4 per thread, coalesced) ----
#pragma unroll
    for (int i = 0; i < 8; ++i) {
        int id = t + i * 256;
        int row = id >> 6, c4 = id & 63;
        float4 f = *((const float4*)(features + (size_t)(n0 + row) * C_DIM) + c4);
        *(ushort4*)&Fbuf[row * LDSTR + c4 * 4] = f4bf(f);
    }
    __syncthreads();   // (1) F + ilab ready

    const int wave = t >> 6, lane = t & 63, r16 = lane & 15, quad = lane >> 4;

    // ---- GEMM1: Q[32][wave*64..+64] = F @ Wq^T (fully unrolled K) ----
    float4v acc[2][4];
#pragma unroll
    for (int mt = 0; mt < 2; ++mt)
#pragma unroll
        for (int nt = 0; nt < 4; ++nt)
#pragma unroll
            for (int r = 0; r < 4; ++r) acc[mt][nt][r] = 0.f;

#pragma unroll
    for (int ks = 0; ks < 8; ++ks) {
        const int c0 = ks * 32 + quad * 8;
        short8 afr[2], bfr[4];
#pragma unroll
        for (int mt = 0; mt < 2; ++mt)
            afr[mt] = *(const short8*)&Fbuf[(mt * 16 + r16) * LDSTR + c0];
#pragma unroll
        for (int nt = 0; nt < 4; ++nt) {
            int drow = wave * 64 + nt * 16 + r16;
            bfr[nt] = *(const short8*)&Wqb[(size_t)drow * C_DIM + c0];
        }
#pragma unroll
        for (int mt = 0; mt < 2; ++mt)
#pragma unroll
            for (int nt = 0; nt < 4; ++nt)
                acc[mt][nt] = __builtin_amdgcn_mfma_f32_16x16x32_bf16(
                    afr[mt], bfr[nt], acc[mt][nt], 0, 0, 0);
    }
    __syncthreads();   // (2) all F reads done; buffer reusable for Q

    // ---- Q (+bq) over Fbuf ----
#pragma unroll
    for (int nt = 0; nt < 4; ++nt) {
        const int col = wave * 64 + nt * 16 + r16;
        const float bq = in_proj_b[col];
#pragma unroll
        for (int mt = 0; mt < 2; ++mt)
#pragma unroll
            for (int r = 0; r < 4; ++r) {
                int row = mt * 16 + quad * 4 + r;
                Fbuf[row * LDSTR + col] = f2bf(acc[mt][nt][r] + bq);
            }
    }
    __syncthreads();   // (3) Q ready

    // ---- attention: 8 lanes/pixel, lane s covers 32 channels ----
    const int p = t >> 3, s = t & 7;
    const int aidx = max(ilab[p] - 1, 0);
    const unsigned short* Kp = Kb + (size_t)aidx * L_ANCH * C_DIM;
    const unsigned short* Vp = Vb + (size_t)aidx * L_ANCH * C_DIM;

    float sc[L_ANCH];
#pragma unroll
    for (int l = 0; l < L_ANCH; ++l) {
        float a0 = 0.f, a1 = 0.f, a2 = 0.f, a3 = 0.f;
#pragma unroll
        for (int ch = 0; ch < 4; ++ch) {
            int cbase = s * 32 + ch * 8;
            short8 kv = *(const short8*)&Kp[l * C_DIM + cbase];
            short8 qv = *(const short8*)&Fbuf[p * LDSTR + cbase];
            float pacc = 0.f;
#pragma unroll
            for (int j = 0; j < 8; ++j)
                pacc += bf2f(((const unsigned short*)&qv)[j]) *
                        bf2f(((const unsigned short*)&kv)[j]);
            if (ch == 0) a0 = pacc; else if (ch == 1) a1 = pacc;
            else if (ch == 2) a2 = pacc; else a3 = pacc;
        }
        float partial = (a0 + a1) + (a2 + a3);
        partial += __shfl_down(partial, 1);
        partial += __shfl_down(partial, 2);
        partial += __shfl_down(partial, 4);
        sc[l] = partial;                 // valid on s==0
    }

    float attn[L_ANCH];
    if (s == 0) {
        const float scale = 0.0625f;     // 1/sqrt(256)
        float mx = -1e30f;
#pragma unroll
        for (int l = 0; l < L_ANCH; ++l) { sc[l] *= scale; mx = fmaxf(mx, sc[l]); }
        float sum = 0.f;
#pragma unroll
        for (int l = 0; l < L_ANCH; ++l) { attn[l] = __expf(sc[l] - mx); sum += attn[l]; }
        float inv = 1.f / sum;
#pragma unroll
        for (int l = 0; l < L_ANCH; ++l) attn[l] *= inv;
    }
    const int base_lane = lane & ~7;
    float a_bc[L_ANCH];
#pragma unroll
    for (int l = 0; l < L_ANCH; ++l) a_bc[l] = __shfl(attn[l], base_lane);

    // ---- prefetch epilogue feature reloads (latency absorbed by barrier 4/5) ----
    float4 fpre[8];
#pragma unroll
    for (int i = 0; i < 8; ++i) {
        int id = t + i * 256;
        int row = id >> 6, c4 = id & 63;
        fpre[i] = *((const float4*)(features + (size_t)(n0 + row) * C_DIM) + c4);
    }

    // ---- O = attn @ V, in-place over the Q bytes this thread read ----
#pragma unroll
    for (int ch = 0; ch < 4; ++ch) {
        int cbase = s * 32 + ch * 8;
        float o8[8];
#pragma unroll
        for (int j = 0; j < 8; ++j) o8[j] = 0.f;
#pragma unroll
        for (int l = 0; l < L_ANCH; ++l) {
            short8 vv = *(const short8*)&Vp[l * C_DIM + cbase];
            float av = a_bc[l];
#pragma unroll
            for (int j = 0; j < 8; ++j)
                o8[j] += av * bf2f(((const unsigned short*)&vv)[j]);
        }
        unsigned short pk[8];
#pragma unroll
        for (int j = 0; j < 8; ++j) pk[j] = f2bf(o8[j]);
        *(short8*)&Fbuf[p * LDSTR + cbase] = *(const short8*)pk;
    }
    __syncthreads();   // (4) O ready

    // ---- GEMM2: O @ out_w^T (fully unrolled K) ----
    float4v acc2[2][4];
#pragma unroll
    for (int mt = 0; mt < 2; ++mt)
#pragma unroll
        for (int nt = 0; nt < 4; ++nt)
#pragma unroll
            for (int r = 0; r < 4; ++r) acc2[mt][nt][r] = 0.f;

#pragma unroll
    for (int ks = 0; ks < 8; ++ks) {
        const int c0 = ks * 32 + quad * 8;
        short8 afr[2], bfr[4];
#pragma unroll
        for (int mt = 0; mt < 2; ++mt)
            afr[mt] = *(const short8*)&Fbuf[(mt * 16 + r16) * LDSTR + c0];
#pragma unroll
        for (int nt = 0; nt < 4; ++nt) {
            int drow = wave * 64 + nt * 16 + r16;
            bfr[nt] = *(const short8*)&Owb[(size_t)drow * C_DIM + c0];
        }
#pragma unroll
        for (int mt = 0; mt < 2; ++mt)
#pragma unroll
            for (int nt = 0; nt < 4; ++nt)
                acc2[mt][nt] = __builtin_amdgcn_mfma_f32_16x16x32_bf16(
                    afr[mt], bfr[nt], acc2[mt][nt], 0, 0, 0);
    }

    // ---- masked val+bias -> stash ----
#pragma unroll
    for (int nt = 0; nt < 4; ++nt) {
        const int col = wave * 64 + nt * 16 + r16;
        const float bo = out_b[col];
#pragma unroll
        for (int mt = 0; mt < 2; ++mt)
#pragma unroll
            for (int r = 0; r < 4; ++r) {
                int row = mt * 16 + quad * 4 + r;
                float val = (ilab[row] > 0) ? (acc2[mt][nt][r] + bo) : 0.f;
                Stash[row * SSTR + col] = f2bf(val);
            }
    }
    __syncthreads();   // (5) stash ready

    // ---- vectorized residual epilogue (features from prefetch regs) ----
#pragma unroll
    for (int i = 0; i < 8; ++i) {
        int id = t + i * 256;
        int row = id >> 6, c4 = id & 63;
        size_t gi = (size_t)(n0 + row) * C_DIM + c4 * 4;
        ushort4 v = *(const ushort4*)&Stash[row * SSTR + c4 * 4];
        float4 o;
        o.x = fpre[i].x + bf2f(v.x); o.y = fpre[i].y + bf2f(v.y);
        o.z = fpre[i].z + bf2f(v.z); o.w = fpre[i].w + bf2f(v.w);
        *(float4*)(out + gi) = o;
    }
}

// ---------------------------------------------------------------------------
extern "C" void kernel_launch(void* const* d_in, const int* in_sizes, int n_in,
                              void* d_out, int out_size, void* d_ws, size_t ws_size,
                              hipStream_t stream) {
    const float* anchors   = (const float*)d_in[0];
    const float* features  = (const float*)d_in[1];
    const int*   inst      = (const int*)d_in[2];
    const float* in_proj_w = (const float*)d_in[3];
    const float* in_proj_b = (const float*)d_in[4];
    const float* out_w     = (const float*)d_in[5];
    const float* out_b     = (const float*)d_in[6];
    float* out = (float*)d_out;

    unsigned short* Kb  = (unsigned short*)d_ws;              // 512*256 bf16
    unsigned short* Vb  = Kb  + M_INST * L_ANCH * C_DIM;      // 512*256
    unsigned short* Wqb = Vb  + M_INST * L_ANCH * C_DIM;      // 256*256
    unsigned short* Owb = Wqb + C_DIM * C_DIM;                // 256*256

    prep_kernel<<<160, 256, 0, stream>>>(anchors, in_proj_w, in_proj_b, out_w,
                                         Kb, Vb, Wqb, Owb);
    fused_kernel<<<NPIX / TILE_M, 256, 0, stream>>>(
        features, inst, in_proj_b, out_b, Wqb, Owb, Kb, Vb, out);
}

// Round 8
// 136.160 us; speedup vs baseline: 1.3045x; 1.3045x over previous
//
#include <hip/hip_runtime.h>
#include <stdint.h>

#define C_DIM   256
#define L_ANCH  8
#define M_INST  64
#define NPIX    32768
#define LDSTR   264      // A-tile row stride (shorts)
#define WSTR    40       // prep W-tile row stride (shorts)
#define TSTR    80       // transpose tile row stride (shorts), 160 B (16B-mult)

typedef __attribute__((ext_vector_type(8))) short  short8;   // 8 x bf16
typedef __attribute__((ext_vector_type(4))) float  float4v;  // MFMA C/D

__device__ __forceinline__ float bf2f(unsigned short b) {
    union { unsigned u; float f; } x; x.u = ((unsigned)b) << 16; return x.f;
}
__device__ __forceinline__ unsigned short f2bf(float f) {
    union { unsigned u; float f; } x; x.f = f;
    unsigned u = x.u;
    return (unsigned short)((u + 0x7FFFu + ((u >> 16) & 1u)) >> 16);  // RNE
}
__device__ __forceinline__ ushort4 f4bf(float4 f) {
    ushort4 v; v.x = f2bf(f.x); v.y = f2bf(f.y); v.z = f2bf(f.z); v.w = f2bf(f.w);
    return v;
}

// ---------------------------------------------------------------------------
// P1: blocks 0..31   : K/V = anchors @ {Wk,Wv}^T + b  via MFMA (bf16)
//     blocks 32..95  : convert out_w -> Owb (bf16, row-major)
//     blocks 96..111 : convert Wq -> WqT (bf16, TRANSPOSED) via LDS 64x64 tile
// ---------------------------------------------------------------------------
__global__ __launch_bounds__(256) void prep1_kernel(
    const float* __restrict__ anchors, const float* __restrict__ in_proj_w,
    const float* __restrict__ in_proj_b, const float* __restrict__ out_w,
    unsigned short* __restrict__ Kb, unsigned short* __restrict__ Vb,
    unsigned short* __restrict__ WqT, unsigned short* __restrict__ Owb)
{
    __shared__ unsigned short Abuf[32 * LDSTR];
    __shared__ unsigned short Wtile[4][64 * WSTR];
    __shared__ unsigned short Ttile[64 * TSTR];
    const int b = blockIdx.x, t = threadIdx.x;

    if (b >= 96) {           // ---- WqT transpose: 16 blocks, 64x64 tiles ----
        const int tidx = b - 96;
        const int r0 = (tidx >> 2) * 64, c0 = (tidx & 3) * 64;
#pragma unroll
        for (int i = 0; i < 4; ++i) {
            int id = t + i * 256;            // 1024 float4 chunks
            int row = id >> 4, c4 = id & 15;
            float4 f = *(const float4*)&in_proj_w[(size_t)(r0 + row) * C_DIM + c0 + c4 * 4];
            Ttile[(c4 * 4 + 0) * TSTR + row] = f2bf(f.x);
            Ttile[(c4 * 4 + 1) * TSTR + row] = f2bf(f.y);
            Ttile[(c4 * 4 + 2) * TSTR + row] = f2bf(f.z);
            Ttile[(c4 * 4 + 3) * TSTR + row] = f2bf(f.w);
        }
        __syncthreads();
#pragma unroll
        for (int i = 0; i < 2; ++i) {
            int id = t + i * 256;            // 512 short8 chunks
            int cc = id >> 3, ch = id & 7;
            *(short8*)&WqT[(size_t)(c0 + cc) * C_DIM + r0 + ch * 8] =
                *(const short8*)&Ttile[cc * TSTR + ch * 8];
        }
        return;
    }

    if (b >= 32) {           // ---- Owb convert: 64 blocks ----
        const int id = (b - 32) * 256 + t;   // 16384 float4 chunks
        float4 f = *((const float4*)out_w + id);
        *((ushort4*)Owb + id) = f4bf(f);
        return;
    }

    // ---- K/V MFMA GEMM (verified R2 structure) ----
    const int mat = b >> 4, tile = b & 15, m0 = tile * 32;
#pragma unroll
    for (int i = 0; i < 8; ++i) {
        int id = t + i * 256;
        int row = id >> 6, c4 = id & 63;
        float4 f = *((const float4*)(anchors + (size_t)(m0 + row) * C_DIM) + c4);
        *(ushort4*)&Abuf[row * LDSTR + c4 * 4] = f4bf(f);
    }
    __syncthreads();

    const int wave = t >> 6, lane = t & 63, r16 = lane & 15, quad = lane >> 4;
    const int wbase = C_DIM + mat * C_DIM + wave * 64;
    unsigned short* Wl = &Wtile[wave][0];

    float4v acc[2][4];
#pragma unroll
    for (int mt = 0; mt < 2; ++mt)
#pragma unroll
        for (int nt = 0; nt < 4; ++nt)
#pragma unroll
            for (int r = 0; r < 4; ++r) acc[mt][nt][r] = 0.f;

    for (int ks = 0; ks < 8; ++ks) {
        const int rr = lane >> 3, cc = lane & 7;
#pragma unroll
        for (int i = 0; i < 8; ++i) {
            int row = rr + i * 8;
            float4 f = *((const float4*)(in_proj_w + (size_t)(wbase + row) * C_DIM + ks * 32) + cc);
            *(ushort4*)&Wl[row * WSTR + cc * 4] = f4bf(f);
        }
        const int c0 = ks * 32 + quad * 8;
        short8 afr[2], bfr[4];
#pragma unroll
        for (int mt = 0; mt < 2; ++mt)
            afr[mt] = *(const short8*)&Abuf[(mt * 16 + r16) * LDSTR + c0];
#pragma unroll
        for (int nt = 0; nt < 4; ++nt)
            bfr[nt] = *(const short8*)&Wl[(nt * 16 + r16) * WSTR + quad * 8];
#pragma unroll
        for (int mt = 0; mt < 2; ++mt)
#pragma unroll
            for (int nt = 0; nt < 4; ++nt)
                acc[mt][nt] = __builtin_amdgcn_mfma_f32_16x16x32_bf16(
                    afr[mt], bfr[nt], acc[mt][nt], 0, 0, 0);
    }

    unsigned short* dst = mat ? Vb : Kb;
#pragma unroll
    for (int nt = 0; nt < 4; ++nt) {
        const int col = wave * 64 + nt * 16 + r16;
        const float bias = in_proj_b[C_DIM + mat * C_DIM + col];
#pragma unroll
        for (int mt = 0; mt < 2; ++mt)
#pragma unroll
            for (int r = 0; r < 4; ++r) {
                int row = m0 + mt * 16 + quad * 4 + r;
                dst[(size_t)row * C_DIM + col] = f2bf(acc[mt][nt][r] + bias);
            }
    }
}

// ---------------------------------------------------------------------------
// P2: blocks 0..15 : G = K @ WqT^T (bf16) + g0 = K . bq (fp32)
//     blocks 16..31: U = V @ Owb^T (bf16)
//   (standard verified MFMA pattern; A staged in LDS, B-frags from global)
// ---------------------------------------------------------------------------
__global__ __launch_bounds__(256) void prep2_kernel(
    const unsigned short* __restrict__ Kb, const unsigned short* __restrict__ Vb,
    const unsigned short* __restrict__ WqT, const unsigned short* __restrict__ Owb,
    const float* __restrict__ in_proj_b,
    unsigned short* __restrict__ G, unsigned short* __restrict__ U,
    float* __restrict__ g0)
{
    __shared__ unsigned short Abuf[32 * LDSTR];
    const int b = blockIdx.x, t = threadIdx.x;
    const int isG = (b < 16) ? 1 : 0;
    const int tile = b & 15, m0 = tile * 32;
    const unsigned short* src = isG ? Kb : Vb;
    const unsigned short* W   = isG ? WqT : Owb;
    unsigned short* dst       = isG ? G : U;

    // stage 32 rows of A (bf16 copy)
#pragma unroll
    for (int i = 0; i < 4; ++i) {
        int id = t + i * 256;            // 1024 short8 chunks
        int row = id >> 5, c8 = id & 31;
        *(short8*)&Abuf[row * LDSTR + c8 * 8] =
            *(const short8*)&src[(size_t)(m0 + row) * C_DIM + c8 * 8];
    }
    __syncthreads();

    const int wave = t >> 6, lane = t & 63, r16 = lane & 15, quad = lane >> 4;

    // g0 = K . bq (G blocks only)
    if (isG) {
        const int grow = t >> 3, gs = t & 7;
        float gp = 0.f;
#pragma unroll
        for (int c = 0; c < 32; ++c)
            gp += bf2f(Abuf[grow * LDSTR + gs * 32 + c]) * in_proj_b[gs * 32 + c];
        gp += __shfl_down(gp, 1);
        gp += __shfl_down(gp, 2);
        gp += __shfl_down(gp, 4);
        if (gs == 0) g0[m0 + grow] = gp;
    }

    float4v acc[2][4];
#pragma unroll
    for (int mt = 0; mt < 2; ++mt)
#pragma unroll
        for (int nt = 0; nt < 4; ++nt)
#pragma unroll
            for (int r = 0; r < 4; ++r) acc[mt][nt][r] = 0.f;

    for (int ks = 0; ks < 8; ++ks) {
        const int c0 = ks * 32 + quad * 8;
        short8 afr[2], bfr[4];
#pragma unroll
        for (int mt = 0; mt < 2; ++mt)
            afr[mt] = *(const short8*)&Abuf[(mt * 16 + r16) * LDSTR + c0];
#pragma unroll
        for (int nt = 0; nt < 4; ++nt)
            bfr[nt] = *(const short8*)&W[(size_t)(wave * 64 + nt * 16 + r16) * C_DIM + c0];
#pragma unroll
        for (int mt = 0; mt < 2; ++mt)
#pragma unroll
            for (int nt = 0; nt < 4; ++nt)
                acc[mt][nt] = __builtin_amdgcn_mfma_f32_16x16x32_bf16(
                    afr[mt], bfr[nt], acc[mt][nt], 0, 0, 0);
    }

#pragma unroll
    for (int nt = 0; nt < 4; ++nt) {
        const int col = wave * 64 + nt * 16 + r16;
#pragma unroll
        for (int mt = 0; mt < 2; ++mt)
#pragma unroll
            for (int r = 0; r < 4; ++r) {
                int row = m0 + mt * 16 + quad * 4 + r;
                dst[(size_t)row * C_DIM + col] = f2bf(acc[mt][nt][r]);
            }
    }
}

// ---------------------------------------------------------------------------
// gather: out = f + mask * (softmax((G[m].f + g0)/16) @ U[m] + out_b)
//   8 lanes/pixel, 32 pixels/block, 1024 blocks. No LDS, no barriers.
// ---------------------------------------------------------------------------
__global__ __launch_bounds__(256) void gather_kernel(
    const float* __restrict__ features, const int* __restrict__ inst,
    const float* __restrict__ out_b,
    const unsigned short* __restrict__ G, const unsigned short* __restrict__ U,
    const float* __restrict__ g0, float* __restrict__ out)
{
    const int t = threadIdx.x;
    const int p = t >> 3, s = t & 7;
    const int n = blockIdx.x * 32 + p;
    const int lab = inst[n];
    const int m = max(lab - 1, 0);
    const unsigned short* Gp = G + (size_t)m * (L_ANCH * C_DIM) + s * 32;
    const unsigned short* Up = U + (size_t)m * (L_ANCH * C_DIM) + s * 32;

    // f slice: 32 fp32 (channels s*32 .. s*32+32)
    float fr[32];
    const float4* fp = (const float4*)(features + (size_t)n * C_DIM + s * 32);
#pragma unroll
    for (int i = 0; i < 8; ++i) *(float4*)&fr[i * 4] = fp[i];

    // scores: 8 dots of 32 (partial), shfl-reduced over the 8 lanes
    float sc[L_ANCH];
#pragma unroll
    for (int l = 0; l < L_ANCH; ++l) {
        short8 gv0 = *(const short8*)(Gp + l * C_DIM);
        short8 gv1 = *(const short8*)(Gp + l * C_DIM + 8);
        short8 gv2 = *(const short8*)(Gp + l * C_DIM + 16);
        short8 gv3 = *(const short8*)(Gp + l * C_DIM + 24);
        float a0 = 0.f, a1 = 0.f, a2 = 0.f, a3 = 0.f;
#pragma unroll
        for (int j = 0; j < 8; ++j) {
            a0 += bf2f(((const unsigned short*)&gv0)[j]) * fr[j];
            a1 += bf2f(((const unsigned short*)&gv1)[j]) * fr[8 + j];
            a2 += bf2f(((const unsigned short*)&gv2)[j]) * fr[16 + j];
            a3 += bf2f(((const unsigned short*)&gv3)[j]) * fr[24 + j];
        }
        float partial = (a0 + a1) + (a2 + a3);
        partial += __shfl_down(partial, 1);
        partial += __shfl_down(partial, 2);
        partial += __shfl_down(partial, 4);
        sc[l] = partial;                 // valid on s==0
    }

    float attn[L_ANCH];
    if (s == 0) {
        const float scale = 0.0625f;     // 1/sqrt(256)
        float mx = -1e30f;
#pragma unroll
        for (int l = 0; l < L_ANCH; ++l) {
            sc[l] = (sc[l] + g0[m * L_ANCH + l]) * scale;
            mx = fmaxf(mx, sc[l]);
        }
        float sum = 0.f;
#pragma unroll
        for (int l = 0; l < L_ANCH; ++l) { attn[l] = __expf(sc[l] - mx); sum += attn[l]; }
        float inv = 1.f / sum;
#pragma unroll
        for (int l = 0; l < L_ANCH; ++l) attn[l] *= inv;
    }
    const int base_lane = (t & 63) & ~7;
    float a_bc[L_ANCH];
#pragma unroll
    for (int l = 0; l < L_ANCH; ++l) a_bc[l] = __shfl(attn[l], base_lane);

    // combine: y = sum_l attn_l * U_l  (32 channels per lane)
    float y[32];
#pragma unroll
    for (int c = 0; c < 32; ++c) y[c] = 0.f;
#pragma unroll
    for (int l = 0; l < L_ANCH; ++l) {
        const float av = a_bc[l];
        short8 uv0 = *(const short8*)(Up + l * C_DIM);
        short8 uv1 = *(const short8*)(Up + l * C_DIM + 8);
        short8 uv2 = *(const short8*)(Up + l * C_DIM + 16);
        short8 uv3 = *(const short8*)(Up + l * C_DIM + 24);
#pragma unroll
        for (int j = 0; j < 8; ++j) {
            y[j]      += av * bf2f(((const unsigned short*)&uv0)[j]);
            y[8 + j]  += av * bf2f(((const unsigned short*)&uv1)[j]);
            y[16 + j] += av * bf2f(((const unsigned short*)&uv2)[j]);
            y[24 + j] += av * bf2f(((const unsigned short*)&uv3)[j]);
        }
    }

    // epilogue: out = f + mask * (y + out_b)
    float4* op = (float4*)(out + (size_t)n * C_DIM + s * 32);
    const float4* obp = (const float4*)(out_b + s * 32);
#pragma unroll
    for (int i = 0; i < 8; ++i) {
        float4 ob = obp[i];
        float4 o;
        o.x = fr[i * 4 + 0] + ((lab > 0) ? (y[i * 4 + 0] + ob.x) : 0.f);
        o.y = fr[i * 4 + 1] + ((lab > 0) ? (y[i * 4 + 1] + ob.y) : 0.f);
        o.z = fr[i * 4 + 2] + ((lab > 0) ? (y[i * 4 + 2] + ob.z) : 0.f);
        o.w = fr[i * 4 + 3] + ((lab > 0) ? (y[i * 4 + 3] + ob.w) : 0.f);
        op[i] = o;
    }
}

// ---------------------------------------------------------------------------
extern "C" void kernel_launch(void* const* d_in, const int* in_sizes, int n_in,
                              void* d_out, int out_size, void* d_ws, size_t ws_size,
                              hipStream_t stream) {
    const float* anchors   = (const float*)d_in[0];
    const float* features  = (const float*)d_in[1];
    const int*   inst      = (const int*)d_in[2];
    const float* in_proj_w = (const float*)d_in[3];
    const float* in_proj_b = (const float*)d_in[4];
    const float* out_w     = (const float*)d_in[5];
    const float* out_b     = (const float*)d_in[6];
    float* out = (float*)d_out;

    unsigned short* Kb  = (unsigned short*)d_ws;              // 512*256 bf16
    unsigned short* Vb  = Kb  + M_INST * L_ANCH * C_DIM;      // 512*256
    unsigned short* WqT = Vb  + M_INST * L_ANCH * C_DIM;      // 256*256 (transposed)
    unsigned short* Owb = WqT + C_DIM * C_DIM;                // 256*256
    unsigned short* G   = Owb + C_DIM * C_DIM;                // 512*256
    unsigned short* U   = G   + M_INST * L_ANCH * C_DIM;      // 512*256
    float*          g0  = (float*)(U + M_INST * L_ANCH * C_DIM); // 512 fp32

    prep1_kernel<<<112, 256, 0, stream>>>(anchors, in_proj_w, in_proj_b, out_w,
                                          Kb, Vb, WqT, Owb);
    prep2_kernel<<<32, 256, 0, stream>>>(Kb, Vb, WqT, Owb, in_proj_b, G, U, g0);
    gather_kernel<<<NPIX / 32, 256, 0, stream>>>(features, inst, out_b, G, U, g0, out);
}

// Round 9
// 122.392 us; speedup vs baseline: 1.4513x; 1.1125x over previous
//
#include <hip/hip_runtime.h>
#include <stdint.h>

#define C_DIM   256
#define L_ANCH  8
#define M_INST  64
#define NPIX    32768
#define LDSTR   264      // A-tile row stride (shorts)
#define WSTR    40       // prep W-tile row stride (shorts)
#define TSTR    80       // transpose tile row stride (shorts)

typedef __attribute__((ext_vector_type(8))) short  short8;   // 8 x bf16
typedef __attribute__((ext_vector_type(4))) float  float4v;  // MFMA C/D

__device__ __forceinline__ float bf2f(unsigned short b) {
    union { unsigned u; float f; } x; x.u = ((unsigned)b) << 16; return x.f;
}
__device__ __forceinline__ unsigned short f2bf(float f) {
    union { unsigned u; float f; } x; x.f = f;
    unsigned u = x.u;
    return (unsigned short)((u + 0x7FFFu + ((u >> 16) & 1u)) >> 16);  // RNE
}
__device__ __forceinline__ ushort4 f4bf(float4 f) {
    ushort4 v; v.x = f2bf(f.x); v.y = f2bf(f.y); v.z = f2bf(f.z); v.w = f2bf(f.w);
    return v;
}

// ---------------------------------------------------------------------------
// P1: blocks 0..63    : K/V = anchors @ {Wk,Wv}^T + b via MFMA
//                       (b>>5 = mat, (b>>1)&15 = 32-row tile, b&1 = col half)
//     blocks 64..127  : convert out_w -> Owb (bf16)
//     blocks 128..143 : Wq -> WqT (bf16 TRANSPOSED) via LDS 64x64 tile
// ---------------------------------------------------------------------------
__global__ __launch_bounds__(256) void prep1_kernel(
    const float* __restrict__ anchors, const float* __restrict__ in_proj_w,
    const float* __restrict__ in_proj_b, const float* __restrict__ out_w,
    unsigned short* __restrict__ Kb, unsigned short* __restrict__ Vb,
    unsigned short* __restrict__ WqT, unsigned short* __restrict__ Owb)
{
    __shared__ unsigned short Abuf[32 * LDSTR];
    __shared__ unsigned short Wtile[4][32 * WSTR];
    __shared__ unsigned short Ttile[64 * TSTR];
    const int b = blockIdx.x, t = threadIdx.x;

    if (b >= 128) {          // ---- WqT transpose: 16 blocks, 64x64 tiles ----
        const int tidx = b - 128;
        const int r0 = (tidx >> 2) * 64, c0 = (tidx & 3) * 64;
#pragma unroll
        for (int i = 0; i < 4; ++i) {
            int id = t + i * 256;            // 1024 float4 chunks
            int row = id >> 4, c4 = id & 15;
            float4 f = *(const float4*)&in_proj_w[(size_t)(r0 + row) * C_DIM + c0 + c4 * 4];
            Ttile[(c4 * 4 + 0) * TSTR + row] = f2bf(f.x);
            Ttile[(c4 * 4 + 1) * TSTR + row] = f2bf(f.y);
            Ttile[(c4 * 4 + 2) * TSTR + row] = f2bf(f.z);
            Ttile[(c4 * 4 + 3) * TSTR + row] = f2bf(f.w);
        }
        __syncthreads();
#pragma unroll
        for (int i = 0; i < 2; ++i) {
            int id = t + i * 256;            // 512 short8 chunks
            int cc = id >> 3, ch = id & 7;
            *(short8*)&WqT[(size_t)(c0 + cc) * C_DIM + r0 + ch * 8] =
                *(const short8*)&Ttile[cc * TSTR + ch * 8];
        }
        return;
    }

    if (b >= 64) {           // ---- Owb convert: 64 blocks ----
        const int id = (b - 64) * 256 + t;   // 16384 float4 chunks
        float4 f = *((const float4*)out_w + id);
        *((ushort4*)Owb + id) = f4bf(f);
        return;
    }

    // ---- K/V MFMA GEMM: 64 blocks (mat x 16 tiles x 2 col-halves) ----
    const int mat = b >> 5, tile = (b >> 1) & 15, half = b & 1;
    const int m0 = tile * 32;
#pragma unroll
    for (int i = 0; i < 8; ++i) {
        int id = t + i * 256;
        int row = id >> 6, c4 = id & 63;
        float4 f = *((const float4*)(anchors + (size_t)(m0 + row) * C_DIM) + c4);
        *(ushort4*)&Abuf[row * LDSTR + c4 * 4] = f4bf(f);
    }
    __syncthreads();

    const int wave = t >> 6, lane = t & 63, r16 = lane & 15, quad = lane >> 4;
    const int colbase = half * 128 + wave * 32;                 // 32 cols per wave
    const int wbase = C_DIM + mat * C_DIM + colbase;            // W row range
    unsigned short* Wl = &Wtile[wave][0];                       // 32 x WSTR

    float4v acc[2][2];
#pragma unroll
    for (int mt = 0; mt < 2; ++mt)
#pragma unroll
        for (int nt = 0; nt < 2; ++nt)
#pragma unroll
            for (int r = 0; r < 4; ++r) acc[mt][nt][r] = 0.f;

    for (int ks = 0; ks < 8; ++ks) {
        const int rr = lane >> 3, cc = lane & 7;
#pragma unroll
        for (int i = 0; i < 4; ++i) {
            int row = rr + i * 8;           // 32 W rows
            float4 f = *((const float4*)(in_proj_w + (size_t)(wbase + row) * C_DIM + ks * 32) + cc);
            *(ushort4*)&Wl[row * WSTR + cc * 4] = f4bf(f);
        }
        const int c0 = ks * 32 + quad * 8;
        short8 afr[2], bfr[2];
#pragma unroll
        for (int mt = 0; mt < 2; ++mt)
            afr[mt] = *(const short8*)&Abuf[(mt * 16 + r16) * LDSTR + c0];
#pragma unroll
        for (int nt = 0; nt < 2; ++nt)
            bfr[nt] = *(const short8*)&Wl[(nt * 16 + r16) * WSTR + quad * 8];
#pragma unroll
        for (int mt = 0; mt < 2; ++mt)
#pragma unroll
            for (int nt = 0; nt < 2; ++nt)
                acc[mt][nt] = __builtin_amdgcn_mfma_f32_16x16x32_bf16(
                    afr[mt], bfr[nt], acc[mt][nt], 0, 0, 0);
    }

    unsigned short* dst = mat ? Vb : Kb;
#pragma unroll
    for (int nt = 0; nt < 2; ++nt) {
        const int col = colbase + nt * 16 + r16;
        const float bias = in_proj_b[C_DIM + mat * C_DIM + col];
#pragma unroll
        for (int mt = 0; mt < 2; ++mt)
#pragma unroll
            for (int r = 0; r < 4; ++r) {
                int row = m0 + mt * 16 + quad * 4 + r;
                dst[(size_t)row * C_DIM + col] = f2bf(acc[mt][nt][r] + bias);
            }
    }
}

// ---------------------------------------------------------------------------
// P2: blocks 0..31 : G = K @ WqT^T + (g0 = K.bq on half==0)
//     blocks 32..63: U = V @ Owb^T
//   (b>>1)&15 = 32-row tile, b&1 = col half; verified MFMA pattern
// ---------------------------------------------------------------------------
__global__ __launch_bounds__(256) void prep2_kernel(
    const unsigned short* __restrict__ Kb, const unsigned short* __restrict__ Vb,
    const unsigned short* __restrict__ WqT, const unsigned short* __restrict__ Owb,
    const float* __restrict__ in_proj_b,
    unsigned short* __restrict__ G, unsigned short* __restrict__ U,
    float* __restrict__ g0)
{
    __shared__ unsigned short Abuf[32 * LDSTR];
    const int b = blockIdx.x, t = threadIdx.x;
    const int isG = (b < 32) ? 1 : 0;
    const int tile = (b >> 1) & 15, half = b & 1;
    const int m0 = tile * 32;
    const unsigned short* src = isG ? Kb : Vb;
    const unsigned short* W   = isG ? WqT : Owb;
    unsigned short* dst       = isG ? G : U;

#pragma unroll
    for (int i = 0; i < 4; ++i) {
        int id = t + i * 256;            // 1024 short8 chunks
        int row = id >> 5, c8 = id & 31;
        *(short8*)&Abuf[row * LDSTR + c8 * 8] =
            *(const short8*)&src[(size_t)(m0 + row) * C_DIM + c8 * 8];
    }
    __syncthreads();

    const int wave = t >> 6, lane = t & 63, r16 = lane & 15, quad = lane >> 4;

    if (isG && half == 0) {
        const int grow = t >> 3, gs = t & 7;
        float gp = 0.f;
#pragma unroll
        for (int c = 0; c < 32; ++c)
            gp += bf2f(Abuf[grow * LDSTR + gs * 32 + c]) * in_proj_b[gs * 32 + c];
        gp += __shfl_down(gp, 1);
        gp += __shfl_down(gp, 2);
        gp += __shfl_down(gp, 4);
        if (gs == 0) g0[m0 + grow] = gp;
    }

    const int colbase = half * 128 + wave * 32;

    float4v acc[2][2];
#pragma unroll
    for (int mt = 0; mt < 2; ++mt)
#pragma unroll
        for (int nt = 0; nt < 2; ++nt)
#pragma unroll
            for (int r = 0; r < 4; ++r) acc[mt][nt][r] = 0.f;

    for (int ks = 0; ks < 8; ++ks) {
        const int c0 = ks * 32 + quad * 8;
        short8 afr[2], bfr[2];
#pragma unroll
        for (int mt = 0; mt < 2; ++mt)
            afr[mt] = *(const short8*)&Abuf[(mt * 16 + r16) * LDSTR + c0];
#pragma unroll
        for (int nt = 0; nt < 2; ++nt)
            bfr[nt] = *(const short8*)&W[(size_t)(colbase + nt * 16 + r16) * C_DIM + c0];
#pragma unroll
        for (int mt = 0; mt < 2; ++mt)
#pragma unroll
            for (int nt = 0; nt < 2; ++nt)
                acc[mt][nt] = __builtin_amdgcn_mfma_f32_16x16x32_bf16(
                    afr[mt], bfr[nt], acc[mt][nt], 0, 0, 0);
    }

#pragma unroll
    for (int nt = 0; nt < 2; ++nt) {
        const int col = colbase + nt * 16 + r16;
#pragma unroll
        for (int mt = 0; mt < 2; ++mt)
#pragma unroll
            for (int r = 0; r < 4; ++r) {
                int row = m0 + mt * 16 + quad * 4 + r;
                dst[(size_t)row * C_DIM + col] = f2bf(acc[mt][nt][r]);
            }
    }
}

// ---------------------------------------------------------------------------
// gather: out = f + mask * (softmax((G[m].f + g0)/16) @ U[m] + out_b)
//   16 lanes/pixel, 16 pixels/block, 2048 blocks. No LDS, no barriers.
// ---------------------------------------------------------------------------
__global__ __launch_bounds__(256) void gather_kernel(
    const float* __restrict__ features, const int* __restrict__ inst,
    const float* __restrict__ out_b,
    const unsigned short* __restrict__ G, const unsigned short* __restrict__ U,
    const float* __restrict__ g0, float* __restrict__ out)
{
    const int t = threadIdx.x;
    const int p = t >> 4, s = t & 15;          // 16 lanes per pixel
    const int n = blockIdx.x * 16 + p;
    const int lab = inst[n];
    const int m = max(lab - 1, 0);
    const unsigned short* Gp = G + (size_t)m * (L_ANCH * C_DIM) + s * 16;
    const unsigned short* Up = U + (size_t)m * (L_ANCH * C_DIM) + s * 16;

    // f slice: 16 fp32 (channels s*16 .. s*16+16)
    float fr[16];
    const float4* fp = (const float4*)(features + (size_t)n * C_DIM + s * 16);
#pragma unroll
    for (int i = 0; i < 4; ++i) *(float4*)&fr[i * 4] = fp[i];

    float sc[L_ANCH];
#pragma unroll
    for (int l = 0; l < L_ANCH; ++l) {
        short8 gv0 = *(const short8*)(Gp + l * C_DIM);
        short8 gv1 = *(const short8*)(Gp + l * C_DIM + 8);
        float a0 = 0.f, a1 = 0.f;
#pragma unroll
        for (int j = 0; j < 8; ++j) {
            a0 += bf2f(((const unsigned short*)&gv0)[j]) * fr[j];
            a1 += bf2f(((const unsigned short*)&gv1)[j]) * fr[8 + j];
        }
        float partial = a0 + a1;
        partial += __shfl_down(partial, 1);
        partial += __shfl_down(partial, 2);
        partial += __shfl_down(partial, 4);
        partial += __shfl_down(partial, 8);
        sc[l] = partial;                 // valid on s==0
    }

    float attn[L_ANCH];
    if (s == 0) {
        const float scale = 0.0625f;     // 1/sqrt(256)
        float mx = -1e30f;
#pragma unroll
        for (int l = 0; l < L_ANCH; ++l) {
            sc[l] = (sc[l] + g0[m * L_ANCH + l]) * scale;
            mx = fmaxf(mx, sc[l]);
        }
        float sum = 0.f;
#pragma unroll
        for (int l = 0; l < L_ANCH; ++l) { attn[l] = __expf(sc[l] - mx); sum += attn[l]; }
        float inv = 1.f / sum;
#pragma unroll
        for (int l = 0; l < L_ANCH; ++l) attn[l] *= inv;
    }
    const int base_lane = (t & 63) & ~15;
    float a_bc[L_ANCH];
#pragma unroll
    for (int l = 0; l < L_ANCH; ++l) a_bc[l] = __shfl(attn[l], base_lane);

    float y[16];
#pragma unroll
    for (int c = 0; c < 16; ++c) y[c] = 0.f;
#pragma unroll
    for (int l = 0; l < L_ANCH; ++l) {
        const float av = a_bc[l];
        short8 uv0 = *(const short8*)(Up + l * C_DIM);
        short8 uv1 = *(const short8*)(Up + l * C_DIM + 8);
#pragma unroll
        for (int j = 0; j < 8; ++j) {
            y[j]     += av * bf2f(((const unsigned short*)&uv0)[j]);
            y[8 + j] += av * bf2f(((const unsigned short*)&uv1)[j]);
        }
    }

    const float fm = (lab > 0) ? 1.f : 0.f;
    float4* op = (float4*)(out + (size_t)n * C_DIM + s * 16);
    const float4* obp = (const float4*)(out_b + s * 16);
#pragma unroll
    for (int i = 0; i < 4; ++i) {
        float4 ob = obp[i];
        float4 o;
        o.x = fr[i * 4 + 0] + fm * (y[i * 4 + 0] + ob.x);
        o.y = fr[i * 4 + 1] + fm * (y[i * 4 + 1] + ob.y);
        o.z = fr[i * 4 + 2] + fm * (y[i * 4 + 2] + ob.z);
        o.w = fr[i * 4 + 3] + fm * (y[i * 4 + 3] + ob.w);
        op[i] = o;
    }
}

// ---------------------------------------------------------------------------
extern "C" void kernel_launch(void* const* d_in, const int* in_sizes, int n_in,
                              void* d_out, int out_size, void* d_ws, size_t ws_size,
                              hipStream_t stream) {
    const float* anchors   = (const float*)d_in[0];
    const float* features  = (const float*)d_in[1];
    const int*   inst      = (const int*)d_in[2];
    const float* in_proj_w = (const float*)d_in[3];
    const float* in_proj_b = (const float*)d_in[4];
    const float* out_w     = (const float*)d_in[5];
    const float* out_b     = (const float*)d_in[6];
    float* out = (float*)d_out;

    unsigned short* Kb  = (unsigned short*)d_ws;              // 512*256 bf16
    unsigned short* Vb  = Kb  + M_INST * L_ANCH * C_DIM;      // 512*256
    unsigned short* WqT = Vb  + M_INST * L_ANCH * C_DIM;      // 256*256 (transposed)
    unsigned short* Owb = WqT + C_DIM * C_DIM;                // 256*256
    unsigned short* G   = Owb + C_DIM * C_DIM;                // 512*256
    unsigned short* U   = G   + M_INST * L_ANCH * C_DIM;      // 512*256
    float*          g0  = (float*)(U + M_INST * L_ANCH * C_DIM); // 512 fp32

    prep1_kernel<<<144, 256, 0, stream>>>(anchors, in_proj_w, in_proj_b, out_w,
                                          Kb, Vb, WqT, Owb);
    prep2_kernel<<<64, 256, 0, stream>>>(Kb, Vb, WqT, Owb, in_proj_b, G, U, g0);
    gather_kernel<<<NPIX / 16, 256, 0, stream>>>(features, inst, out_b, G, U, g0, out);
}